// Round 3
// baseline (2558.949 us; speedup 1.0000x reference)
//
#include <hip/hip_runtime.h>
#include <hip/hip_bf16.h>

#define TT 1024
#define HH 128
#define G4 512

typedef float  f32x2 __attribute__((ext_vector_type(2)));
typedef float  f32x4v __attribute__((ext_vector_type(4)));
typedef short  s16x8 __attribute__((ext_vector_type(8)));
typedef int    i32x4 __attribute__((ext_vector_type(4)));
typedef unsigned int u32;
typedef unsigned short u16;

__device__ __forceinline__ float sigm(float x){ return __builtin_amdgcn_rcpf(1.f + __expf(-x)); }
__device__ __forceinline__ float tanh_f(float x){ return 1.f - 2.f*__builtin_amdgcn_rcpf(1.f + __expf(2.f*x)); }

__device__ __forceinline__ float dpp_add(float v, const int ctrl){
    int t;
    switch (ctrl) {  // ctrl must be an ICE for the builtin; call sites pass literals
      case 0xB1:  t = __builtin_amdgcn_update_dpp(0, __float_as_int(v), 0xB1, 0xF, 0xF, true); break;
      case 0x4E:  t = __builtin_amdgcn_update_dpp(0, __float_as_int(v), 0x4E, 0xF, 0xF, true); break;
      case 0x141: t = __builtin_amdgcn_update_dpp(0, __float_as_int(v), 0x141, 0xF, 0xF, true); break;
      default:    t = __builtin_amdgcn_update_dpp(0, __float_as_int(v), 0x140, 0xF, 0xF, true); break;
    }
    return v + __int_as_float(t);
}
// sum over the 8 lanes of an aligned 8-lane group (lane bits 0..2)
__device__ __forceinline__ float red8(float v){
    v = dpp_add(v, 0xB1);    // quad_perm [1,0,3,2]  (xor1)
    v = dpp_add(v, 0x4E);    // quad_perm [2,3,0,1]  (xor2)
    v = dpp_add(v, 0x141);   // row_half_mirror      (xor4, quads uniform)
    return v;
}

// pack f32 -> (bf16_hi << 16) | bf16_lo(residual)
__device__ __forceinline__ u32 pack_bf16x2(float h){
    __hip_bfloat16 bh = __float2bfloat16(h);
    float hf = __bfloat162float(bh);
    __hip_bfloat16 bl = __float2bfloat16(h - hf);
    return (u32(__bfloat16_as_ushort(bh)) << 16) | u32(__bfloat16_as_ushort(bl));
}

// ---------------- prep: split W_ih1 into bf16 hi/lo planes, [512][128] ------
__global__ void prep(const float* __restrict__ Wih1, u16* __restrict__ Bhi, u16* __restrict__ Blo)
{
    const int i = blockIdx.x * 256 + threadIdx.x;  // 0..65535
    const float w = Wih1[i];
    __hip_bfloat16 bh = __float2bfloat16(w);
    float hf = __bfloat162float(bh);
    __hip_bfloat16 bl = __float2bfloat16(w - hf);
    Bhi[i] = __bfloat16_as_ushort(bh);
    Blo[i] = __bfloat16_as_ushort(bl);
}

// ============================ layer 0 =======================================
// 1024 threads: thread = (j = tid>>3, s = tid&7). 4 gates {j,j+128,j+256,j+384},
// k-slice of 16. Weights in 64 VGPRs. DPP cross-slice reduce. 1 barrier/step.
__global__ __launch_bounds__(1024, 4) void lstm0(
    const float* __restrict__ x, const float* __restrict__ Wih,
    const float* __restrict__ Whh, const float* __restrict__ bih,
    const float* __restrict__ bhh, u32* __restrict__ h0out)
{
    const int b   = blockIdx.x;
    const int tid = threadIdx.x;
    const int j   = tid >> 3;
    const int s   = tid & 7;

    __shared__ __align__(16) float xS[TT];       // 4 KB
    __shared__ __align__(16) float hS[2][HH];    // double-buffered h

    // staggered conflict-free read offsets
    int offs[4];
#pragma unroll
    for (int r = 0; r < 4; ++r) offs[r] = 16*s + 4*((r + (s>>1)) & 3);

    f32x2 wif[4][4], wgo[4][4];
#pragma unroll
    for (int r = 0; r < 4; ++r) {
#pragma unroll
        for (int e = 0; e < 4; ++e) {
            const int k = offs[r] + e;
            wif[r][e] = (f32x2){ Whh[(size_t)j*HH + k],        Whh[(size_t)(j+128)*HH + k] };
            wgo[r][e] = (f32x2){ Whh[(size_t)(j+256)*HH + k],  Whh[(size_t)(j+384)*HH + k] };
        }
    }
    const float4 bb = { bih[j]     + bhh[j],
                        bih[j+128] + bhh[j+128],
                        bih[j+256] + bhh[j+256],
                        bih[j+384] + bhh[j+384] };
    const float4 wx = { Wih[j], Wih[j+128], Wih[j+256], Wih[j+384] };

    xS[tid] = x[(size_t)b * TT + tid];
    if (tid < 256) ((float*)hS)[tid] = 0.f;
    float c_reg = 0.f;
    __syncthreads();

    u32* hb = h0out + (size_t)b * TT * HH;

    for (int t = 0; t < TT; ++t) {
        const float* hcur = hS[t & 1];
        f32x2 aif = (f32x2){0.f, 0.f}, ago = (f32x2){0.f, 0.f};
#pragma unroll
        for (int r = 0; r < 4; ++r) {
            const float4 hv = *(const float4*)(hcur + offs[r]);
            aif = __builtin_elementwise_fma((f32x2){hv.x,hv.x}, wif[r][0], aif);
            ago = __builtin_elementwise_fma((f32x2){hv.x,hv.x}, wgo[r][0], ago);
            aif = __builtin_elementwise_fma((f32x2){hv.y,hv.y}, wif[r][1], aif);
            ago = __builtin_elementwise_fma((f32x2){hv.y,hv.y}, wgo[r][1], ago);
            aif = __builtin_elementwise_fma((f32x2){hv.z,hv.z}, wif[r][2], aif);
            ago = __builtin_elementwise_fma((f32x2){hv.z,hv.z}, wgo[r][2], ago);
            aif = __builtin_elementwise_fma((f32x2){hv.w,hv.w}, wif[r][3], aif);
            ago = __builtin_elementwise_fma((f32x2){hv.w,hv.w}, wgo[r][3], ago);
        }
        const float xv = xS[t];
        const float gi = sigm (red8(aif.x) + fmaf(xv, wx.x, bb.x));
        const float gf = sigm (red8(aif.y) + fmaf(xv, wx.y, bb.y));
        const float gg = tanh_f(red8(ago.x) + fmaf(xv, wx.z, bb.z));
        const float go = sigm (red8(ago.y) + fmaf(xv, wx.w, bb.w));
        c_reg = fmaf(gf, c_reg, gi * gg);
        const float h = go * tanh_f(c_reg);
        if (s == 0) {
            hS[(t + 1) & 1][j] = h;
            hb[(size_t)t * HH + j] = pack_bf16x2(h);
        }
        __syncthreads();
    }
}

// ============================ layer 1 + FC ==================================
__global__ __launch_bounds__(1024, 4) void lstm1(
    const u32* __restrict__ h0in, const u16* __restrict__ Bhi,
    const u16* __restrict__ Blo,  const float* __restrict__ Whh,
    const float* __restrict__ bih, const float* __restrict__ bhh,
    const float* __restrict__ fcw, const float* __restrict__ fcb,
    float* __restrict__ out)
{
    const int b   = blockIdx.x;
    const int tid = threadIdx.x;
    const int j   = tid >> 3;
    const int s   = tid & 7;
    const int wv  = tid >> 6;
    const int lane = tid & 63;

    __shared__ __align__(16) u32   h0uS[32][HH];   // 16 KB, bank-swizzled
    __shared__ __align__(16) float xgS[32 * G4];   // 64 KB
    __shared__ __align__(16) float hS[2][HH];      // 1 KB
    __shared__ __align__(16) float fcP[2][16];

    int offs[4];
#pragma unroll
    for (int r = 0; r < 4; ++r) offs[r] = 16*s + 4*((r + (s>>1)) & 3);

    f32x2 wif[4][4], wgo[4][4];
#pragma unroll
    for (int r = 0; r < 4; ++r) {
#pragma unroll
        for (int e = 0; e < 4; ++e) {
            const int k = offs[r] + e;
            wif[r][e] = (f32x2){ Whh[(size_t)j*HH + k],        Whh[(size_t)(j+128)*HH + k] };
            wgo[r][e] = (f32x2){ Whh[(size_t)(j+256)*HH + k],  Whh[(size_t)(j+384)*HH + k] };
        }
    }
    const float4 bb = { bih[j]     + bhh[j],
                        bih[j+128] + bhh[j+128],
                        bih[j+256] + bhh[j+256],
                        bih[j+384] + bhh[j+384] };
    const float fcwj = fcw[j];
    const float fcbv = fcb[0];
    const int bp_addr = ((lane ^ 32) << 2);       // for ds_bpermute (bytes)

    // proj tiling
    const int rt = wv & 1;                        // A row-tile (steps 0-15 / 16-31)
    const int ctbase = (wv >> 1) * 4;             // 4 col-tiles per wave
    const int lrow = lane & 15, lquad = lane >> 4;

    if (tid < 256) ((float*)hS)[tid] = 0.f;
    float c_reg = 0.f;
    __syncthreads();

    const u32* hbu = h0in + (size_t)b * TT * HH;
    float* ob = out + (size_t)b * TT;

    for (int t0 = 0; t0 < TT; t0 += 32) {
        // ---- stage h0 chunk into LDS (bank-swizzled on k bits 3..4) ----
        {
            const int r = tid >> 5;               // 0..31
            const int k = (tid & 31) * 4;         // 0..124
            const i32x4 v = *(const i32x4*)(hbu + (size_t)t0 * HH + r * HH + k);
            *(i32x4*)&h0uS[r][k ^ ((r & 3) << 3)] = v;
        }
        __syncthreads();

        // ---- proj: xg[32][512] via split-bf16 MFMA ----
        {
            const int arow = rt * 16 + lrow;
            const int aswz = (arow & 3) << 3;
#pragma unroll
            for (int cp = 0; cp < 2; ++cp) {
                const int ct0 = ctbase + cp * 2;
                const int col0 = ct0 * 16 + lrow;
                const int col1 = col0 + 16;
                f32x4v a0 = {0.f,0.f,0.f,0.f}, a1 = {0.f,0.f,0.f,0.f};
#pragma unroll
                for (int kk = 0; kk < 4; ++kk) {
                    const int kb = kk * 32 + lquad * 8;
                    const u32* ap = &h0uS[arow][kb ^ aswz];
                    const i32x4 u0 = *(const i32x4*)ap;
                    const i32x4 u1 = *(const i32x4*)(ap + 4);
                    i32x4 fh, fl;
                    fh.x = __builtin_amdgcn_perm(u0.y, u0.x, 0x07060302u);
                    fh.y = __builtin_amdgcn_perm(u0.w, u0.z, 0x07060302u);
                    fh.z = __builtin_amdgcn_perm(u1.y, u1.x, 0x07060302u);
                    fh.w = __builtin_amdgcn_perm(u1.w, u1.z, 0x07060302u);
                    fl.x = __builtin_amdgcn_perm(u0.y, u0.x, 0x05040100u);
                    fl.y = __builtin_amdgcn_perm(u0.w, u0.z, 0x05040100u);
                    fl.z = __builtin_amdgcn_perm(u1.y, u1.x, 0x05040100u);
                    fl.w = __builtin_amdgcn_perm(u1.w, u1.z, 0x05040100u);
                    const s16x8 ah = __builtin_bit_cast(s16x8, fh);
                    const s16x8 al = __builtin_bit_cast(s16x8, fl);
                    const s16x8 bh0 = *(const s16x8*)&Bhi[(size_t)col0 * HH + kb];
                    const s16x8 bl0 = *(const s16x8*)&Blo[(size_t)col0 * HH + kb];
                    const s16x8 bh1 = *(const s16x8*)&Bhi[(size_t)col1 * HH + kb];
                    const s16x8 bl1 = *(const s16x8*)&Blo[(size_t)col1 * HH + kb];
                    a0 = __builtin_amdgcn_mfma_f32_16x16x32_bf16(ah, bh0, a0, 0, 0, 0);
                    a0 = __builtin_amdgcn_mfma_f32_16x16x32_bf16(al, bh0, a0, 0, 0, 0);
                    a0 = __builtin_amdgcn_mfma_f32_16x16x32_bf16(ah, bl0, a0, 0, 0, 0);
                    a1 = __builtin_amdgcn_mfma_f32_16x16x32_bf16(ah, bh1, a1, 0, 0, 0);
                    a1 = __builtin_amdgcn_mfma_f32_16x16x32_bf16(al, bh1, a1, 0, 0, 0);
                    a1 = __builtin_amdgcn_mfma_f32_16x16x32_bf16(ah, bl1, a1, 0, 0, 0);
                }
                // C layout: col = lane&15, row = (lane>>4)*4 + e
                const int xb0 = (col0 & 127) * 4 + (col0 >> 7);
                const int xb1 = (col1 & 127) * 4 + (col1 >> 7);
                const int irow = rt * 16 + lquad * 4;
#pragma unroll
                for (int e = 0; e < 4; ++e) {
                    xgS[(irow + e) * G4 + xb0] = a0[e];
                    xgS[(irow + e) * G4 + xb1] = a1[e];
                }
            }
        }
        __syncthreads();

        // ---- 32 recurrent steps, 1 barrier each ----
        for (int i = 0; i < 32; ++i) {
            const int t = t0 + i;
            // deferred FC output for step t-1 (wave 15)
            if (wv == 15 && t > 0) {
                float v = (lane < 16) ? fcP[(t & 1) ^ 1][lane] : 0.f;
                v = red8(v);
                v = dpp_add(v, 0x140);            // row_mirror: fold 8..15 into 0..7
                if (lane == 0) ob[t - 1] = v + fcbv;
            }
            const float* hcur = hS[t & 1];
            f32x2 aif = (f32x2){0.f, 0.f}, ago = (f32x2){0.f, 0.f};
#pragma unroll
            for (int r = 0; r < 4; ++r) {
                const float4 hv = *(const float4*)(hcur + offs[r]);
                aif = __builtin_elementwise_fma((f32x2){hv.x,hv.x}, wif[r][0], aif);
                ago = __builtin_elementwise_fma((f32x2){hv.x,hv.x}, wgo[r][0], ago);
                aif = __builtin_elementwise_fma((f32x2){hv.y,hv.y}, wif[r][1], aif);
                ago = __builtin_elementwise_fma((f32x2){hv.y,hv.y}, wgo[r][1], ago);
                aif = __builtin_elementwise_fma((f32x2){hv.z,hv.z}, wif[r][2], aif);
                ago = __builtin_elementwise_fma((f32x2){hv.z,hv.z}, wgo[r][2], ago);
                aif = __builtin_elementwise_fma((f32x2){hv.w,hv.w}, wif[r][3], aif);
                ago = __builtin_elementwise_fma((f32x2){hv.w,hv.w}, wgo[r][3], ago);
            }
            const float4 xv = *(const float4*)&xgS[i * G4 + 4 * j];
            const float gi = sigm (red8(aif.x) + xv.x + bb.x);
            const float gf = sigm (red8(aif.y) + xv.y + bb.y);
            const float gg = tanh_f(red8(ago.x) + xv.z + bb.z);
            const float go = sigm (red8(ago.y) + xv.w + bb.w);
            c_reg = fmaf(gf, c_reg, gi * gg);
            const float h = go * tanh_f(c_reg);
            if (s == 0) hS[(t + 1) & 1][j] = h;
            // FC partial: p uniform across the 8 s-lanes of each j
            float pf = h * fcwj;
            pf = dpp_add(pf, 0x140);                                   // + other j in row16
            pf += __int_as_float(__builtin_amdgcn_ds_swizzle(__float_as_int(pf), 0x401F)); // xor16
            pf += __int_as_float(__builtin_amdgcn_ds_bpermute(bp_addr, __float_as_int(pf))); // xor32
            if (lane == 0) fcP[t & 1][wv] = pf;
            __syncthreads();
        }
    }
    // epilogue: FC for t = TT-1
    if (wv == 15) {
        float v = (lane < 16) ? fcP[(TT - 1) & 1][lane] : 0.f;
        v = red8(v);
        v = dpp_add(v, 0x140);
        if (lane == 0) ob[TT - 1] = v + fcbv;
    }
}

extern "C" void kernel_launch(void* const* d_in, const int* in_sizes, int n_in,
                              void* d_out, int out_size, void* d_ws, size_t ws_size,
                              hipStream_t stream)
{
    const float* x    = (const float*)d_in[0];
    const float* Wih0 = (const float*)d_in[1];
    const float* Whh0 = (const float*)d_in[2];
    const float* bih0 = (const float*)d_in[3];
    const float* bhh0 = (const float*)d_in[4];
    const float* Wih1 = (const float*)d_in[5];
    const float* Whh1 = (const float*)d_in[6];
    const float* bih1 = (const float*)d_in[7];
    const float* bhh1 = (const float*)d_in[8];
    const float* fcw  = (const float*)d_in[9];
    const float* fcb  = (const float*)d_in[10];
    float* out = (float*)d_out;

    u32* h0 = (u32*)d_ws;                              // 256*1024*128 u32 = 128 MiB
    u16* Bhi = (u16*)((char*)d_ws + (size_t)256 * TT * HH * 4);   // 128 KiB
    u16* Blo = Bhi + (size_t)G4 * HH;                  // 128 KiB

    prep <<<256, 256, 0, stream>>>(Wih1, Bhi, Blo);
    lstm0<<<256, 1024, 0, stream>>>(x, Wih0, Whh0, bih0, bhh0, h0);
    lstm1<<<256, 1024, 0, stream>>>(h0, Bhi, Blo, Whh1, bih1, bhh1, fcw, fcb, out);
}

// Round 5
// 2325.028 us; speedup vs baseline: 1.1006x; 1.1006x over previous
//
#include <hip/hip_runtime.h>
#include <hip/hip_bf16.h>

#define TT 1024
#define HH 128
#define G4 512

typedef float  f32x2 __attribute__((ext_vector_type(2)));
typedef float  f32x4v __attribute__((ext_vector_type(4)));
typedef short  s16x8 __attribute__((ext_vector_type(8)));
typedef int    i32x4 __attribute__((ext_vector_type(4)));
typedef unsigned int u32;
typedef unsigned short u16;

__device__ __forceinline__ float sigm(float x){ return __builtin_amdgcn_rcpf(1.f + __expf(-x)); }
__device__ __forceinline__ float tanh_f(float x){ return 1.f - 2.f*__builtin_amdgcn_rcpf(1.f + __expf(2.f*x)); }

// opaque producer: value must be in a VGPR here and cannot be re-materialized
__device__ __forceinline__ void keepv(f32x2 &v){ asm volatile("" : "+v"(v)); }

__device__ __forceinline__ float dpp_add(float v, const int ctrl){
    int t;
    switch (ctrl) {
      case 0xB1:  t = __builtin_amdgcn_update_dpp(0, __float_as_int(v), 0xB1, 0xF, 0xF, true); break;
      case 0x4E:  t = __builtin_amdgcn_update_dpp(0, __float_as_int(v), 0x4E, 0xF, 0xF, true); break;
      case 0x141: t = __builtin_amdgcn_update_dpp(0, __float_as_int(v), 0x141, 0xF, 0xF, true); break;
      default:    t = __builtin_amdgcn_update_dpp(0, __float_as_int(v), 0x140, 0xF, 0xF, true); break;
    }
    return v + __int_as_float(t);
}
__device__ __forceinline__ float red8(float v){
    v = dpp_add(v, 0xB1);
    v = dpp_add(v, 0x4E);
    v = dpp_add(v, 0x141);
    return v;
}

__device__ __forceinline__ u32 pack_bf16x2(float h){
    __hip_bfloat16 bh = __float2bfloat16(h);
    float hf = __bfloat162float(bh);
    __hip_bfloat16 bl = __float2bfloat16(h - hf);
    return (u32(__bfloat16_as_ushort(bh)) << 16) | u32(__bfloat16_as_ushort(bl));
}

// ---------------- prep: split W_ih1 into bf16 hi/lo planes ------------------
// PERMUTED row order: plane row r holds original gate (r&3)*128 + (r>>2), so
// proj output position 4j+c == gate c*128+j (the recurrent reader's layout).
__global__ void prep(const float* __restrict__ Wih1, u16* __restrict__ Bhi, u16* __restrict__ Blo)
{
    const int i = blockIdx.x * 256 + threadIdx.x;   // 0..65535
    const int r = i >> 7;                           // dest row 0..511
    const int k = i & 127;
    const int g = (r & 3) * 128 + (r >> 2);         // source gate row
    const float w = Wih1[(size_t)g * HH + k];
    __hip_bfloat16 bh = __float2bfloat16(w);
    float hf = __bfloat162float(bh);
    __hip_bfloat16 bl = __float2bfloat16(w - hf);
    Bhi[i] = __bfloat16_as_ushort(bh);
    Blo[i] = __bfloat16_as_ushort(bl);
}

// ============================ layer 0 =======================================
__global__ __attribute__((amdgpu_flat_work_group_size(1024,1024), amdgpu_waves_per_eu(4,4)))
void lstm0(
    const float* __restrict__ x, const float* __restrict__ Wih,
    const float* __restrict__ Whh, const float* __restrict__ bih,
    const float* __restrict__ bhh, u32* __restrict__ h0out)
{
    const int b   = blockIdx.x;
    const int tid = threadIdx.x;
    const int j   = tid >> 3;
    const int s   = tid & 7;

    __shared__ __align__(16) float xS[TT];
    __shared__ __align__(16) float hS[2][HH];

    int offs[4];
#pragma unroll
    for (int r = 0; r < 4; ++r) offs[r] = 16*s + 4*((r + (s>>1)) & 3);

    f32x2 wif[4][4], wgo[4][4];
#pragma unroll
    for (int r = 0; r < 4; ++r) {
#pragma unroll
        for (int e = 0; e < 4; ++e) {
            const int k = offs[r] + e;
            wif[r][e] = (f32x2){ Whh[(size_t)j*HH + k],        Whh[(size_t)(j+128)*HH + k] };
            wgo[r][e] = (f32x2){ Whh[(size_t)(j+256)*HH + k],  Whh[(size_t)(j+384)*HH + k] };
        }
    }
#pragma unroll
    for (int r = 0; r < 4; ++r)
#pragma unroll
        for (int e = 0; e < 4; ++e) { keepv(wif[r][e]); keepv(wgo[r][e]); }

    const float4 bb = { bih[j]     + bhh[j],
                        bih[j+128] + bhh[j+128],
                        bih[j+256] + bhh[j+256],
                        bih[j+384] + bhh[j+384] };
    const float4 wx = { Wih[j], Wih[j+128], Wih[j+256], Wih[j+384] };

    xS[tid] = x[(size_t)b * TT + tid];
    if (tid < 256) ((float*)hS)[tid] = 0.f;
    float c_reg = 0.f;
    __syncthreads();

    u32* hb = h0out + (size_t)b * TT * HH;

    for (int t = 0; t < TT; ++t) {
        const float* hcur = hS[t & 1];
        f32x2 aif = (f32x2){0.f, 0.f}, ago = (f32x2){0.f, 0.f};
#pragma unroll
        for (int r = 0; r < 4; ++r) {
            const float4 hv = *(const float4*)(hcur + offs[r]);
            aif = __builtin_elementwise_fma((f32x2){hv.x,hv.x}, wif[r][0], aif);
            ago = __builtin_elementwise_fma((f32x2){hv.x,hv.x}, wgo[r][0], ago);
            aif = __builtin_elementwise_fma((f32x2){hv.y,hv.y}, wif[r][1], aif);
            ago = __builtin_elementwise_fma((f32x2){hv.y,hv.y}, wgo[r][1], ago);
            aif = __builtin_elementwise_fma((f32x2){hv.z,hv.z}, wif[r][2], aif);
            ago = __builtin_elementwise_fma((f32x2){hv.z,hv.z}, wgo[r][2], ago);
            aif = __builtin_elementwise_fma((f32x2){hv.w,hv.w}, wif[r][3], aif);
            ago = __builtin_elementwise_fma((f32x2){hv.w,hv.w}, wgo[r][3], ago);
        }
        const float xv = xS[t];
        const float gi = sigm  (red8(aif.x) + fmaf(xv, wx.x, bb.x));
        const float gf = sigm  (red8(aif.y) + fmaf(xv, wx.y, bb.y));
        const float gg = tanh_f(red8(ago.x) + fmaf(xv, wx.z, bb.z));
        const float go = sigm  (red8(ago.y) + fmaf(xv, wx.w, bb.w));
        c_reg = fmaf(gf, c_reg, gi * gg);
        const float h = go * tanh_f(c_reg);
        if (s == 0) {
            hS[(t + 1) & 1][j] = h;
            hb[(size_t)t * HH + j] = pack_bf16x2(h);
        }
        __syncthreads();
    }
}

// ============================ layer 1 + FC ==================================
__global__ __attribute__((amdgpu_flat_work_group_size(1024,1024), amdgpu_waves_per_eu(4,4)))
void lstm1(
    const u32* __restrict__ h0in, const u16* __restrict__ Bhi,
    const u16* __restrict__ Blo,  const float* __restrict__ Whh,
    const float* __restrict__ bih, const float* __restrict__ bhh,
    const float* __restrict__ fcw, const float* __restrict__ fcb,
    float* __restrict__ out)
{
    const int b    = blockIdx.x;
    const int tid  = threadIdx.x;
    const int j    = tid >> 3;
    const int s    = tid & 7;
    const int wv   = tid >> 6;
    const int lane = tid & 63;

    __shared__ __align__(16) u16   hhS[32][HH];    // 8 KB, swizzled (k ^ ((r&7)<<4))
    __shared__ __align__(16) u16   hlS[32][HH];    // 8 KB
    __shared__ __align__(16) float xgS[32 * G4];   // 64 KB, swizzled (g ^ ((i&7)<<2))
    __shared__ __align__(16) float hS[2][HH];
    __shared__ __align__(16) float fcP[2][16];

    int offs[4];
#pragma unroll
    for (int r = 0; r < 4; ++r) offs[r] = 16*s + 4*((r + (s>>1)) & 3);

    f32x2 wif[4][4], wgo[4][4];
#pragma unroll
    for (int r = 0; r < 4; ++r) {
#pragma unroll
        for (int e = 0; e < 4; ++e) {
            const int k = offs[r] + e;
            wif[r][e] = (f32x2){ Whh[(size_t)j*HH + k],        Whh[(size_t)(j+128)*HH + k] };
            wgo[r][e] = (f32x2){ Whh[(size_t)(j+256)*HH + k],  Whh[(size_t)(j+384)*HH + k] };
        }
    }
#pragma unroll
    for (int r = 0; r < 4; ++r)
#pragma unroll
        for (int e = 0; e < 4; ++e) { keepv(wif[r][e]); keepv(wgo[r][e]); }

    const float4 bb = { bih[j]     + bhh[j],
                        bih[j+128] + bhh[j+128],
                        bih[j+256] + bhh[j+256],
                        bih[j+384] + bhh[j+384] };
    const float fcwj = fcw[j];
    const float fcbv = fcb[0];
    const int bp_addr = ((lane ^ 32) << 2);

    // staging ids: thread -> (row sr, 4 u32 at sk)
    const int sr = tid >> 5;           // 0..31
    const int sk = (tid & 31) * 4;     // element index base
    // proj ids
    const int lr = lane & 15, lq = lane >> 4;

    if (tid < 256) ((float*)hS)[tid] = 0.f;
    float c_reg = 0.f;
    __syncthreads();

    const u32* hbu = h0in + (size_t)b * TT * HH;
    float* ob = out + (size_t)b * TT;

    for (int t0 = 0; t0 < TT; t0 += 32) {
        // ---- stage h0 chunk as bf16 hi/lo planes (unpack via v_perm) ----
        {
            const i32x4 v = *(const i32x4*)&hbu[(size_t)(t0 + sr) * HH + sk];
            const u32 hi01 = __builtin_amdgcn_perm(v.y, v.x, 0x07060302u);
            const u32 hi23 = __builtin_amdgcn_perm(v.w, v.z, 0x07060302u);
            const u32 lo01 = __builtin_amdgcn_perm(v.y, v.x, 0x05040100u);
            const u32 lo23 = __builtin_amdgcn_perm(v.w, v.z, 0x05040100u);
            const int ks = sk ^ ((sr & 7) << 4);
            *(u32*)&hhS[sr][ks]     = hi01;
            *(u32*)&hhS[sr][ks + 2] = hi23;
            *(u32*)&hlS[sr][ks]     = lo01;
            *(u32*)&hlS[sr][ks + 2] = lo23;
        }
        __syncthreads();

        // ---- proj: xg^T = W_ih(permuted) * h0^T via swapped-operand MFMA ----
        {
#pragma unroll
            for (int gtl = 0; gtl < 2; ++gtl) {
                const int g16 = (wv * 2 + gtl) * 16;
                const u16* pAh = Bhi + (size_t)(g16 + lr) * HH + lq * 8;
                const u16* pAl = Blo + (size_t)(g16 + lr) * HH + lq * 8;
                f32x4v a0 = {0.f,0.f,0.f,0.f}, a1 = {0.f,0.f,0.f,0.f};
#pragma unroll
                for (int kk = 0; kk < 4; ++kk) {
                    const s16x8 Ah = *(const s16x8*)(pAh + kk * 32);
                    const s16x8 Al = *(const s16x8*)(pAl + kk * 32);
                    const int kb = (kk * 32 + lq * 8) ^ ((lr & 7) << 4);
                    const s16x8 Bh0 = *(const s16x8*)&hhS[lr][kb];
                    const s16x8 Bl0 = *(const s16x8*)&hlS[lr][kb];
                    const s16x8 Bh1 = *(const s16x8*)&hhS[16 + lr][kb];
                    const s16x8 Bl1 = *(const s16x8*)&hlS[16 + lr][kb];
                    a0 = __builtin_amdgcn_mfma_f32_16x16x32_bf16(Ah, Bh0, a0, 0, 0, 0);
                    a0 = __builtin_amdgcn_mfma_f32_16x16x32_bf16(Al, Bh0, a0, 0, 0, 0);
                    a0 = __builtin_amdgcn_mfma_f32_16x16x32_bf16(Ah, Bl0, a0, 0, 0, 0);
                    a1 = __builtin_amdgcn_mfma_f32_16x16x32_bf16(Ah, Bh1, a1, 0, 0, 0);
                    a1 = __builtin_amdgcn_mfma_f32_16x16x32_bf16(Al, Bh1, a1, 0, 0, 0);
                    a1 = __builtin_amdgcn_mfma_f32_16x16x32_bf16(Ah, Bl1, a1, 0, 0, 0);
                }
                // lane holds xg[i = itile*16 + lr][pos = gb + e] (permuted gate space)
                const int gb  = g16 + lq * 4;
                const int swz = (lr & 7) << 2;
                *(float4*)&xgS[ lr       * G4 + (gb ^ swz)] = *(float4*)&a0;
                *(float4*)&xgS[(16 + lr) * G4 + (gb ^ swz)] = *(float4*)&a1;
            }
        }
        __syncthreads();

        // ---- 32 recurrent steps, 1 barrier each ----
        for (int i = 0; i < 32; ++i) {
            const int t = t0 + i;
            if (wv == 15 && t > 0) {
                float v = (lane < 16) ? fcP[(t & 1) ^ 1][lane] : 0.f;
                v = red8(v);
                v = dpp_add(v, 0x140);
                if (lane == 0) ob[t - 1] = v + fcbv;
            }
            const float* hcur = hS[t & 1];
            f32x2 aif = (f32x2){0.f, 0.f}, ago = (f32x2){0.f, 0.f};
#pragma unroll
            for (int r = 0; r < 4; ++r) {
                const float4 hv = *(const float4*)(hcur + offs[r]);
                aif = __builtin_elementwise_fma((f32x2){hv.x,hv.x}, wif[r][0], aif);
                ago = __builtin_elementwise_fma((f32x2){hv.x,hv.x}, wgo[r][0], ago);
                aif = __builtin_elementwise_fma((f32x2){hv.y,hv.y}, wif[r][1], aif);
                ago = __builtin_elementwise_fma((f32x2){hv.y,hv.y}, wgo[r][1], ago);
                aif = __builtin_elementwise_fma((f32x2){hv.z,hv.z}, wif[r][2], aif);
                ago = __builtin_elementwise_fma((f32x2){hv.z,hv.z}, wgo[r][2], ago);
                aif = __builtin_elementwise_fma((f32x2){hv.w,hv.w}, wif[r][3], aif);
                ago = __builtin_elementwise_fma((f32x2){hv.w,hv.w}, wgo[r][3], ago);
            }
            const int xswz = (i & 7) << 2;
            const float4 xv = *(const float4*)&xgS[i * G4 + ((4 * j) ^ xswz)];
            const float gi = sigm  (red8(aif.x) + xv.x + bb.x);
            const float gf = sigm  (red8(aif.y) + xv.y + bb.y);
            const float gg = tanh_f(red8(ago.x) + xv.z + bb.z);
            const float go = sigm  (red8(ago.y) + xv.w + bb.w);
            c_reg = fmaf(gf, c_reg, gi * gg);
            const float h = go * tanh_f(c_reg);
            if (s == 0) hS[(t + 1) & 1][j] = h;
            float pf = h * fcwj;
            pf = dpp_add(pf, 0x140);
            pf += __int_as_float(__builtin_amdgcn_ds_swizzle(__float_as_int(pf), 0x401F));
            pf += __int_as_float(__builtin_amdgcn_ds_bpermute(bp_addr, __float_as_int(pf)));
            if (lane == 0) fcP[t & 1][wv] = pf;
            __syncthreads();
        }
    }
    if (wv == 15) {
        float v = (lane < 16) ? fcP[(TT - 1) & 1][lane] : 0.f;
        v = red8(v);
        v = dpp_add(v, 0x140);
        if (lane == 0) ob[TT - 1] = v + fcbv;
    }
}

extern "C" void kernel_launch(void* const* d_in, const int* in_sizes, int n_in,
                              void* d_out, int out_size, void* d_ws, size_t ws_size,
                              hipStream_t stream)
{
    const float* x    = (const float*)d_in[0];
    const float* Wih0 = (const float*)d_in[1];
    const float* Whh0 = (const float*)d_in[2];
    const float* bih0 = (const float*)d_in[3];
    const float* bhh0 = (const float*)d_in[4];
    const float* Wih1 = (const float*)d_in[5];
    const float* Whh1 = (const float*)d_in[6];
    const float* bih1 = (const float*)d_in[7];
    const float* bhh1 = (const float*)d_in[8];
    const float* fcw  = (const float*)d_in[9];
    const float* fcb  = (const float*)d_in[10];
    float* out = (float*)d_out;

    u32* h0  = (u32*)d_ws;                                        // 128 MiB
    u16* Bhi = (u16*)((char*)d_ws + (size_t)256 * TT * HH * 4);   // 128 KiB
    u16* Blo = Bhi + (size_t)G4 * HH;                             // 128 KiB

    prep <<<256, 256, 0, stream>>>(Wih1, Bhi, Blo);
    lstm0<<<256, 1024, 0, stream>>>(x, Wih0, Whh0, bih0, bhh0, h0);
    lstm1<<<256, 1024, 0, stream>>>(h0, Bhi, Blo, Whh1, bih1, bhh1, fcw, fcb, out);
}

// Round 6
// 2207.668 us; speedup vs baseline: 1.1591x; 1.0532x over previous
//
#include <hip/hip_runtime.h>
#include <hip/hip_bf16.h>

#define TT 1024
#define HH 128
#define G4 512

typedef float  f32x2 __attribute__((ext_vector_type(2)));
typedef float  f32x4v __attribute__((ext_vector_type(4)));
typedef short  s16x8 __attribute__((ext_vector_type(8)));
typedef int    i32x4 __attribute__((ext_vector_type(4)));
typedef unsigned int u32;
typedef unsigned short u16;

__device__ __forceinline__ float sigm(float x){ return __builtin_amdgcn_rcpf(1.f + __expf(-x)); }
__device__ __forceinline__ float tanh_f(float x){ return 1.f - 2.f*__builtin_amdgcn_rcpf(1.f + __expf(2.f*x)); }
__device__ __forceinline__ f32x2 sigm2(f32x2 v){ return (f32x2){ sigm(v.x), sigm(v.y) }; }
__device__ __forceinline__ f32x2 tanh2(f32x2 v){ return (f32x2){ tanh_f(v.x), tanh_f(v.y) }; }

__device__ __forceinline__ void keepv(f32x2 &v){ asm volatile("" : "+v"(v)); }

__device__ __forceinline__ float dpp_add(float v, const int ctrl){
    int t;
    switch (ctrl) {
      case 0xB1:  t = __builtin_amdgcn_update_dpp(0, __float_as_int(v), 0xB1, 0xF, 0xF, true); break;
      case 0x4E:  t = __builtin_amdgcn_update_dpp(0, __float_as_int(v), 0x4E, 0xF, 0xF, true); break;
      case 0x141: t = __builtin_amdgcn_update_dpp(0, __float_as_int(v), 0x141, 0xF, 0xF, true); break;
      default:    t = __builtin_amdgcn_update_dpp(0, __float_as_int(v), 0x140, 0xF, 0xF, true); break;
    }
    return v + __int_as_float(t);
}
__device__ __forceinline__ float red8(float v){
    v = dpp_add(v, 0xB1);   // xor1
    v = dpp_add(v, 0x4E);   // xor2
    v = dpp_add(v, 0x141);  // quad<->quad within 8 (quads uniform after xor1/2)
    return v;
}
__device__ __forceinline__ f32x2 red8v(f32x2 v){
    return (f32x2){ red8(v.x), red8(v.y) };
}

__device__ __forceinline__ u32 pack_bf16x2(float h){
    __hip_bfloat16 bh = __float2bfloat16(h);
    float hf = __bfloat162float(bh);
    __hip_bfloat16 bl = __float2bfloat16(h - hf);
    return (u32(__bfloat16_as_ushort(bh)) << 16) | u32(__bfloat16_as_ushort(bl));
}

// ---------------- prep: split W_ih1 into bf16 hi/lo planes ------------------
// PERMUTED row order (verified passing in R5): plane row r holds original gate
// (r&3)*128 + (r>>2), so proj output position 4j+c == gate c*128+j.
__global__ void prep(const float* __restrict__ Wih1, u16* __restrict__ Bhi, u16* __restrict__ Blo)
{
    const int i = blockIdx.x * 256 + threadIdx.x;   // 0..65535
    const int r = i >> 7;
    const int k = i & 127;
    const int g = (r & 3) * 128 + (r >> 2);
    const float w = Wih1[(size_t)g * HH + k];
    __hip_bfloat16 bh = __float2bfloat16(w);
    float hf = __bfloat162float(bh);
    __hip_bfloat16 bl = __float2bfloat16(w - hf);
    Bhi[i] = __bfloat16_as_ushort(bh);
    Blo[i] = __bfloat16_as_ushort(bl);
}

// ============================ layer 0 =======================================
// 512 threads = 8 waves (2/SIMD, 256-VGPR budget via __launch_bounds__(512,2)).
// Thread = (unit pair j0 = 2*(tid>>3), slice s = tid&7). 128 fp32 weights in
// VGPRs: w2[gate c][r][e] = (Whh[c*128+j0][k], Whh[c*128+j0+1][k]).
__global__ __launch_bounds__(512, 2) void lstm0(
    const float* __restrict__ x, const float* __restrict__ Wih,
    const float* __restrict__ Whh, const float* __restrict__ bih,
    const float* __restrict__ bhh, u32* __restrict__ h0out)
{
    const int b   = blockIdx.x;
    const int tid = threadIdx.x;
    const int j0  = (tid >> 3) * 2;
    const int s   = tid & 7;

    __shared__ __align__(16) float xS[TT];
    __shared__ __align__(16) float hS[2][HH];

    int offs[4];
#pragma unroll
    for (int r = 0; r < 4; ++r) offs[r] = 16*s + 4*((r + (s>>1)) & 3);

    f32x2 w2[4][4][4];   // [gate c][r][e] -> 128 VGPRs
#pragma unroll
    for (int c = 0; c < 4; ++c)
#pragma unroll
        for (int r = 0; r < 4; ++r)
#pragma unroll
            for (int e = 0; e < 4; ++e) {
                const int k = offs[r] + e;
                w2[c][r][e] = (f32x2){ Whh[(size_t)(c*128 + j0    ) * HH + k],
                                       Whh[(size_t)(c*128 + j0 + 1) * HH + k] };
            }
#pragma unroll
    for (int c = 0; c < 4; ++c)
#pragma unroll
        for (int r = 0; r < 4; ++r)
#pragma unroll
            for (int e = 0; e < 4; ++e) keepv(w2[c][r][e]);

    f32x2 bb[4], wx[4];
#pragma unroll
    for (int c = 0; c < 4; ++c) {
        bb[c] = (f32x2){ bih[c*128 + j0]     + bhh[c*128 + j0],
                         bih[c*128 + j0 + 1] + bhh[c*128 + j0 + 1] };
        wx[c] = (f32x2){ Wih[c*128 + j0], Wih[c*128 + j0 + 1] };
    }

    xS[tid]       = x[(size_t)b * TT + tid];
    xS[tid + 512] = x[(size_t)b * TT + tid + 512];
    if (tid < 256) ((float*)hS)[tid] = 0.f;
    f32x2 c2 = (f32x2){0.f, 0.f};
    __syncthreads();

    u32* hb = h0out + (size_t)b * TT * HH;

#pragma unroll 1
    for (int t = 0; t < TT; ++t) {
        const float* hcur = hS[t & 1];
        f32x2 acc[4] = { {0.f,0.f}, {0.f,0.f}, {0.f,0.f}, {0.f,0.f} };
#pragma unroll
        for (int r = 0; r < 4; ++r) {
            const float4 hv = *(const float4*)(hcur + offs[r]);
            const float he[4] = { hv.x, hv.y, hv.z, hv.w };
#pragma unroll
            for (int e = 0; e < 4; ++e) {
                const f32x2 hb2 = (f32x2){ he[e], he[e] };
#pragma unroll
                for (int c = 0; c < 4; ++c)
                    acc[c] = __builtin_elementwise_fma(hb2, w2[c][r][e], acc[c]);
            }
        }
#pragma unroll
        for (int c = 0; c < 4; ++c) acc[c] = red8v(acc[c]);

        if (s == 0) {
            const float xv = xS[t];
            const f32x2 xv2 = (f32x2){ xv, xv };
            const f32x2 gi = sigm2 (acc[0] + __builtin_elementwise_fma(xv2, wx[0], bb[0]));
            const f32x2 gf = sigm2 (acc[1] + __builtin_elementwise_fma(xv2, wx[1], bb[1]));
            const f32x2 gg = tanh2 (acc[2] + __builtin_elementwise_fma(xv2, wx[2], bb[2]));
            const f32x2 go = sigm2 (acc[3] + __builtin_elementwise_fma(xv2, wx[3], bb[3]));
            c2 = __builtin_elementwise_fma(gf, c2, gi * gg);
            const f32x2 h2 = go * tanh2(c2);
            *(float2*)&hS[(t + 1) & 1][j0] = *(const float2*)&h2;
            uint2 pp; pp.x = pack_bf16x2(h2.x); pp.y = pack_bf16x2(h2.y);
            *(uint2*)&hb[(size_t)t * HH + j0] = pp;
        }
        __syncthreads();
    }
}

// ============================ layer 1 + FC ==================================
__global__ __launch_bounds__(512, 2) void lstm1(
    const u32* __restrict__ h0in, const u16* __restrict__ Bhi,
    const u16* __restrict__ Blo,  const float* __restrict__ Whh,
    const float* __restrict__ bih, const float* __restrict__ bhh,
    const float* __restrict__ fcw, const float* __restrict__ fcb,
    float* __restrict__ out)
{
    const int b    = blockIdx.x;
    const int tid  = threadIdx.x;
    const int j0   = (tid >> 3) * 2;
    const int s    = tid & 7;
    const int wv   = tid >> 6;
    const int lane = tid & 63;

    __shared__ __align__(16) u16   hhS[32][HH];    // 8 KB, swizzled (k ^ ((r&7)<<4))
    __shared__ __align__(16) u16   hlS[32][HH];    // 8 KB
    __shared__ __align__(16) float xgS[32 * G4];   // 64 KB, swizzled (g ^ ((i&7)<<2))
    __shared__ __align__(16) float hS[2][HH];
    __shared__ __align__(16) float fcP[2][8];

    int offs[4];
#pragma unroll
    for (int r = 0; r < 4; ++r) offs[r] = 16*s + 4*((r + (s>>1)) & 3);

    f32x2 w2[4][4][4];
#pragma unroll
    for (int c = 0; c < 4; ++c)
#pragma unroll
        for (int r = 0; r < 4; ++r)
#pragma unroll
            for (int e = 0; e < 4; ++e) {
                const int k = offs[r] + e;
                w2[c][r][e] = (f32x2){ Whh[(size_t)(c*128 + j0    ) * HH + k],
                                       Whh[(size_t)(c*128 + j0 + 1) * HH + k] };
            }
#pragma unroll
    for (int c = 0; c < 4; ++c)
#pragma unroll
        for (int r = 0; r < 4; ++r)
#pragma unroll
            for (int e = 0; e < 4; ++e) keepv(w2[c][r][e]);

    f32x2 bb[4];
#pragma unroll
    for (int c = 0; c < 4; ++c)
        bb[c] = (f32x2){ bih[c*128 + j0]     + bhh[c*128 + j0],
                         bih[c*128 + j0 + 1] + bhh[c*128 + j0 + 1] };
    const f32x2 fcw2 = (f32x2){ fcw[j0], fcw[j0 + 1] };
    const float fcbv = fcb[0];
    const int bp_addr = ((lane ^ 32) << 2);

    // staging ids
    const int sr  = tid >> 4;          // 0..31
    const int sk8 = (tid & 15) * 8;    // 0..120
    // proj ids
    const int lr = lane & 15, lq = lane >> 4;

    if (tid < 256) ((float*)hS)[tid] = 0.f;
    f32x2 c2 = (f32x2){0.f, 0.f};
    __syncthreads();

    const u32* hbu = h0in + (size_t)b * TT * HH;
    float* ob = out + (size_t)b * TT;

#pragma unroll 1
    for (int t0 = 0; t0 < TT; t0 += 32) {
        // ---- stage h0 chunk as bf16 hi/lo planes (2x i32x4 per thread) ----
        {
            const int sw = (sr & 7) << 4;
#pragma unroll
            for (int g = 0; g < 2; ++g) {
                const i32x4 v = *(const i32x4*)&hbu[(size_t)(t0 + sr) * HH + sk8 + g*4];
                const u32 hi01 = __builtin_amdgcn_perm(v.y, v.x, 0x07060302u);
                const u32 hi23 = __builtin_amdgcn_perm(v.w, v.z, 0x07060302u);
                const u32 lo01 = __builtin_amdgcn_perm(v.y, v.x, 0x05040100u);
                const u32 lo23 = __builtin_amdgcn_perm(v.w, v.z, 0x05040100u);
                const int ks = (sk8 + g*4) ^ sw;
                *(u32*)&hhS[sr][ks]     = hi01;
                *(u32*)&hhS[sr][ks + 2] = hi23;
                *(u32*)&hlS[sr][ks]     = lo01;
                *(u32*)&hlS[sr][ks + 2] = lo23;
            }
        }
        __syncthreads();

        // ---- proj: xg^T = W_ih(permuted) * h0^T, 4 gate-tiles per wave ----
        {
#pragma unroll
            for (int gtl = 0; gtl < 4; ++gtl) {
                const int g16 = (wv * 4 + gtl) * 16;
                const u16* pAh = Bhi + (size_t)(g16 + lr) * HH + lq * 8;
                const u16* pAl = Blo + (size_t)(g16 + lr) * HH + lq * 8;
                f32x4v a0 = {0.f,0.f,0.f,0.f}, a1 = {0.f,0.f,0.f,0.f};
#pragma unroll
                for (int kk = 0; kk < 4; ++kk) {
                    const s16x8 Ah = *(const s16x8*)(pAh + kk * 32);
                    const s16x8 Al = *(const s16x8*)(pAl + kk * 32);
                    const int kb = (kk * 32 + lq * 8) ^ ((lr & 7) << 4);
                    const s16x8 Bh0 = *(const s16x8*)&hhS[lr][kb];
                    const s16x8 Bl0 = *(const s16x8*)&hlS[lr][kb];
                    const s16x8 Bh1 = *(const s16x8*)&hhS[16 + lr][kb];
                    const s16x8 Bl1 = *(const s16x8*)&hlS[16 + lr][kb];
                    a0 = __builtin_amdgcn_mfma_f32_16x16x32_bf16(Ah, Bh0, a0, 0, 0, 0);
                    a0 = __builtin_amdgcn_mfma_f32_16x16x32_bf16(Al, Bh0, a0, 0, 0, 0);
                    a0 = __builtin_amdgcn_mfma_f32_16x16x32_bf16(Ah, Bl0, a0, 0, 0, 0);
                    a1 = __builtin_amdgcn_mfma_f32_16x16x32_bf16(Ah, Bh1, a1, 0, 0, 0);
                    a1 = __builtin_amdgcn_mfma_f32_16x16x32_bf16(Al, Bh1, a1, 0, 0, 0);
                    a1 = __builtin_amdgcn_mfma_f32_16x16x32_bf16(Ah, Bl1, a1, 0, 0, 0);
                }
                const int gb  = g16 + lq * 4;
                const int swz = (lr & 7) << 2;
                *(float4*)&xgS[ lr       * G4 + (gb ^ swz)] = *(float4*)&a0;
                *(float4*)&xgS[(16 + lr) * G4 + (gb ^ swz)] = *(float4*)&a1;
            }
        }
        __syncthreads();

        // ---- 32 recurrent steps, 1 barrier each ----
#pragma unroll 1
        for (int i = 0; i < 32; ++i) {
            const int t = t0 + i;
            if (wv == 7 && t > 0) {     // deferred FC output for step t-1
                float v = (lane < 8) ? fcP[(t & 1) ^ 1][lane] : 0.f;
                v = red8(v);
                if (lane == 0) ob[t - 1] = v + fcbv;
            }
            const float* hcur = hS[t & 1];
            f32x2 acc[4] = { {0.f,0.f}, {0.f,0.f}, {0.f,0.f}, {0.f,0.f} };
#pragma unroll
            for (int r = 0; r < 4; ++r) {
                const float4 hv = *(const float4*)(hcur + offs[r]);
                const float he[4] = { hv.x, hv.y, hv.z, hv.w };
#pragma unroll
                for (int e = 0; e < 4; ++e) {
                    const f32x2 hb2 = (f32x2){ he[e], he[e] };
#pragma unroll
                    for (int c = 0; c < 4; ++c)
                        acc[c] = __builtin_elementwise_fma(hb2, w2[c][r][e], acc[c]);
                }
            }
#pragma unroll
            for (int c = 0; c < 4; ++c) acc[c] = red8v(acc[c]);

            float pf = 0.f;
            if (s == 0) {
                const int xswz = (i & 7) << 2;
                const float4 xv0 = *(const float4*)&xgS[i * G4 + (( 4*j0     ) ^ xswz)];
                const float4 xv1 = *(const float4*)&xgS[i * G4 + (( 4*j0 + 4 ) ^ xswz)];
                const f32x2 gi = sigm2 (acc[0] + (f32x2){xv0.x, xv1.x} + bb[0]);
                const f32x2 gf = sigm2 (acc[1] + (f32x2){xv0.y, xv1.y} + bb[1]);
                const f32x2 gg = tanh2 (acc[2] + (f32x2){xv0.z, xv1.z} + bb[2]);
                const f32x2 go = sigm2 (acc[3] + (f32x2){xv0.w, xv1.w} + bb[3]);
                c2 = __builtin_elementwise_fma(gf, c2, gi * gg);
                const f32x2 h2 = go * tanh2(c2);
                *(float2*)&hS[(t + 1) & 1][j0] = *(const float2*)&h2;
                pf = h2.x * fcw2.x + h2.y * fcw2.y;
            }
            // wave-wide sum of pf (only s==0 lanes nonzero)
            pf = red8(pf);
            pf += __int_as_float(__builtin_amdgcn_ds_swizzle(__float_as_int(pf), 0x201F)); // xor8
            pf += __int_as_float(__builtin_amdgcn_ds_swizzle(__float_as_int(pf), 0x401F)); // xor16
            pf += __int_as_float(__builtin_amdgcn_ds_bpermute(bp_addr, __float_as_int(pf))); // xor32
            if (lane == 0) fcP[t & 1][wv] = pf;
            __syncthreads();
        }
    }
    if (wv == 7) {
        float v = (lane < 8) ? fcP[(TT - 1) & 1][lane] : 0.f;
        v = red8(v);
        if (lane == 0) ob[TT - 1] = v + fcbv;
    }
}

extern "C" void kernel_launch(void* const* d_in, const int* in_sizes, int n_in,
                              void* d_out, int out_size, void* d_ws, size_t ws_size,
                              hipStream_t stream)
{
    const float* x    = (const float*)d_in[0];
    const float* Wih0 = (const float*)d_in[1];
    const float* Whh0 = (const float*)d_in[2];
    const float* bih0 = (const float*)d_in[3];
    const float* bhh0 = (const float*)d_in[4];
    const float* Wih1 = (const float*)d_in[5];
    const float* Whh1 = (const float*)d_in[6];
    const float* bih1 = (const float*)d_in[7];
    const float* bhh1 = (const float*)d_in[8];
    const float* fcw  = (const float*)d_in[9];
    const float* fcb  = (const float*)d_in[10];
    float* out = (float*)d_out;

    u32* h0  = (u32*)d_ws;                                        // 128 MiB
    u16* Bhi = (u16*)((char*)d_ws + (size_t)256 * TT * HH * 4);   // 128 KiB
    u16* Blo = Bhi + (size_t)G4 * HH;                             // 128 KiB

    prep <<<256, 256, 0, stream>>>(Wih1, Bhi, Blo);
    lstm0<<<256, 512, 0, stream>>>(x, Wih0, Whh0, bih0, bhh0, h0);
    lstm1<<<256, 512, 0, stream>>>(h0, Bhi, Blo, Whh1, bih1, bhh1, fcw, fcb, out);
}